// Round 17
// baseline (84.986 us; speedup 1.0000x reference)
//
#include <hip/hip_runtime.h>
#include <math.h>

#define NB    8
#define NN    100
#define NPRED 800
#define MT    20
#define NT    160
#define HW    25600
#define NCLS  80
#define CNT   (NPRED*NT)  // 128000
#define MTILES 25         // 32-row tiles: 25*32 = 800 exactly
#define REGION 5120       // 32*160 entries per (ks, mtile) region

typedef float  f32x4  __attribute__((ext_vector_type(4)));
typedef short  short8 __attribute__((ext_vector_type(8)));
typedef unsigned short u16x8 __attribute__((ext_vector_type(8)));

static __device__ __forceinline__ unsigned short f2bf_rne(float f){
  unsigned u = __float_as_uint(f);
  return (unsigned short)((u + 0x7fffu + ((u >> 16) & 1u)) >> 16);
}
static __device__ __forceinline__ float bf2f(unsigned short h){
  return __uint_as_float(((unsigned)h) << 16);
}

// async global->LDS, 16B per lane
static __device__ __forceinline__ void gload16(const void* g, void* l){
  __builtin_amdgcn_global_load_lds((const __attribute__((address_space(1))) unsigned int*)g,
                                   (__attribute__((address_space(3))) unsigned int*)l, 16, 0, 0);
}

// ---------------- pre-pass: tm fp32 -> bf16 with BAKED XOR swizzle (8-granule chunks, BK=64) ----------------
__global__ __launch_bounds__(256)
void conv_b(const float* __restrict__ tm, unsigned short* __restrict__ Bb,
            float* __restrict__ tnp2){
  const int row = blockIdx.x >> 1, half = blockIdx.x & 1;
  const float4* src = (const float4*)(tm + (size_t)row * HW);
  u16x8* dst = (u16x8*)(Bb + (size_t)row * HW);
  const int sw = row & 7;
  const int g0 = half * 1600, g1 = g0 + 1600;
  float s = 0.f;
  for (int g = g0 + threadIdx.x; g < g1; g += 256){
    float4 x0 = src[g * 2], x1 = src[g * 2 + 1];
    float v[8];
    v[0]=x0.x; v[1]=x0.y; v[2]=x0.z; v[3]=x0.w;
    v[4]=x1.x; v[5]=x1.y; v[6]=x1.z; v[7]=x1.w;
    u16x8 h;
    #pragma unroll
    for (int i = 0; i < 8; i++){ s += v[i]*v[i]; h[i] = f2bf_rne(v[i]); }
    dst[(g & ~7) | ((g & 7) ^ sw)] = h;
  }
  __shared__ float red[256];
  red[threadIdx.x] = s; __syncthreads();
  for (int off = 128; off > 0; off >>= 1){
    if (threadIdx.x < off) red[threadIdx.x] += red[threadIdx.x + off];
    __syncthreads();
  }
  if (threadIdx.x == 0) tnp2[half * NT + row] = red[0];
}

// ---------------- hybrid GEMM, 32-row tiles, single-buffer BK=64, fragment-order bf16 store ----------------
// Tile 32x160x64; 4 waves 2x2, wave tile 16x80. LDS 24 KiB (6 blocks/CU). Grid 2000 (~7.8/CU).
template<int KSTEPS>
__global__ __launch_bounds__(256, 6)
void gemm_hyb(const float* __restrict__ A, const unsigned short* __restrict__ Bb,
              unsigned short* __restrict__ partb, float* __restrict__ pnp, int Kc){
  __shared__ unsigned short sA[32*64];    // 4 KB
  __shared__ unsigned short sB[160*64];   // 20 KB

  const int bid = blockIdx.x;
  const int nb  = gridDim.x;
  const int wg  = ((nb & 7) == 0) ? (bid & 7) * (nb >> 3) + (bid >> 3) : bid;  // XCD-bijective
  const int mtile = wg % MTILES, ks = wg / MTILES;
  const int t = threadIdx.x, lane = t & 63, w = t >> 6;
  const int wr = w >> 1, wc = w & 1;
  const int fr = lane & 15, fq = lane >> 4;
  const int arow = t >> 3, ksl = t & 7;    // A staging: 32 rows x 8 slots
  const int kbase = ks * Kc;

  f32x4 acc[5];
  #pragma unroll
  for (int c = 0; c < 5; c++) acc[c] = (f32x4){0.f,0.f,0.f,0.f};
  float asum = 0.f;

  int brow[5], bg[5];
  #pragma unroll
  for (int i = 0; i < 5; i++){ int s2 = t + i * 256; brow[i] = s2 >> 3; bg[i] = s2 & 7; }

  const float4* ap = (const float4*)(A + (size_t)(mtile*32 + arow) * HW + kbase + ksl * 8);

  for (int step = 0; step < KSTEPS; ++step){
    const int k0 = kbase + step * 64;
    #pragma unroll
    for (int i = 0; i < 5; i++)
      gload16(Bb + (size_t)brow[i] * HW + k0 + bg[i] * 8, sB + (t + i * 256) * 8);
    {
      float4 x0 = ap[step * 16];
      float4 x1 = ap[step * 16 + 1];
      float v[8];
      v[0]=x0.x; v[1]=x0.y; v[2]=x0.z; v[3]=x0.w;
      v[4]=x1.x; v[5]=x1.y; v[6]=x1.z; v[7]=x1.w;
      u16x8 h;
      #pragma unroll
      for (int i = 0; i < 8; i++){ asum += v[i]*v[i]; h[i] = f2bf_rne(v[i]); }
      *(u16x8*)&sA[arow * 64 + ((ksl ^ (arow & 7)) << 3)] = h;
    }
    __syncthreads();
    #pragma unroll
    for (int kk = 0; kk < 2; ++kk){
      const int swz = (((kk * 4 + fq) ^ (fr & 7)) << 3);
      short8 a = *(const short8*)&sA[(wr*16 + fr) * 64 + swz];
      short8 b[5];
      #pragma unroll
      for (int c = 0; c < 5; c++)
        b[c] = *(const short8*)&sB[(wc*80 + c*16 + fr) * 64 + swz];
      #pragma unroll
      for (int c = 0; c < 5; c++)
        acc[c] = __builtin_amdgcn_mfma_f32_16x16x32_bf16(a, b[c], acc[c], 0, 0, 0);
    }
    __syncthreads();
  }

  // pnorm partials
  {
    float s = asum;
    s += __shfl_xor(s, 1); s += __shfl_xor(s, 2); s += __shfl_xor(s, 4);
    if ((t & 7) == 0) pnp[(size_t)ks * NPRED + mtile*32 + arow] = s;
  }

  // fragment-order store: each (c,i) store = 64 lanes x 2B = one full 128B line
  unsigned short* dst = partb + (size_t)ks * CNT + (size_t)mtile * REGION;
  #pragma unroll
  for (int c = 0; c < 5; c++)
    #pragma unroll
    for (int i = 0; i < 4; i++)
      dst[((w * 5 + c) * 4 + i) * 64 + lane] = f2bf_rne(acc[c][i]);
}

// ---------------- finalize (separate kernel; fragment-order partb) ----------------
__global__ __launch_bounds__(256)
void finalize(const unsigned short* __restrict__ partb, int KS,
              const float* __restrict__ pnp, const float* __restrict__ tnp2,
              const float* __restrict__ logits, const int* __restrict__ tgt_ids,
              float* __restrict__ C){
  __shared__ float stn[NT];
  __shared__ float spn[32];
  const int blk = blockIdx.x, t = threadIdx.x;
  const int mtile = blk / 20;
  if (t < NT){
    stn[t] = tnp2[t] + tnp2[NT + t];
  } else if (t < NT + 32){
    const int p = mtile * 32 + (t - NT);
    float s = 0.f;
    for (int ks = 0; ks < KS; ks++) s += pnp[(size_t)ks * NPRED + p];
    spn[t - NT] = s;
  }
  __syncthreads();

  const int idx = blk * 256 + t;
  const int rem  = idx - mtile * REGION;
  const int w2   = rem / 1280;
  const int rem2 = rem - w2 * 1280;
  const int c    = rem2 >> 8;
  const int rem3 = rem2 & 255;
  const int i    = rem3 >> 6;
  const int lane = rem3 & 63;
  const int wr = w2 >> 1, wc = w2 & 1;
  const int fq = lane >> 4, fr = lane & 15;
  const int pl_ = wr*16 + fq*4 + i;
  const int pred = mtile*32 + pl_;
  const int tt   = wc*80 + c*16 + fr;

  const unsigned short* p = partb + idx;
  double d0=0.0, d1=0.0, d2=0.0, d3=0.0;
  int ks = 0;
  for (; ks + 4 <= KS; ks += 4){
    d0 += (double)bf2f(p[(size_t)(ks+0) * CNT]);
    d1 += (double)bf2f(p[(size_t)(ks+1) * CNT]);
    d2 += (double)bf2f(p[(size_t)(ks+2) * CNT]);
    d3 += (double)bf2f(p[(size_t)(ks+3) * CNT]);
  }
  for (; ks < KS; ks++) d0 += (double)bf2f(p[(size_t)ks * CNT]);
  double dot = (d0 + d1) + (d2 + d3);
  double num = 2.0 * dot;
  double den = (double)spn[pl_] + (double)stn[tt];
  double mask_score = -((num + 1e-4) / (den + 1e-4));
  double x = (double)logits[pred * NCLS + tgt_ids[tt]];
  double pl = 1.0 / (1.0 + exp(-x));
  double pos = 0.25 * (1.0 - pl) * (1.0 - pl) * (-log(pl + 1e-8));
  double neg = 0.75 * pl * pl * (-log(1.0 - pl + 1e-8));
  double cv = mask_score * 2.0 + (pos - neg);
  float o = (float)cv;
  if (!isfinite(o)) o = 0.0f;
  C[(size_t)pred * NT + tt] = o;
}

// ---------------- Hungarian (JV): fp32 regs, DPP min + ballot argmin, packed (p,u) ----------------
static __device__ __forceinline__ float sel20(const float c[20], int k){
  const bool b0 = k & 1, b1 = k & 2;
  float t0 = b0 ? c[1]  : c[0],  t1 = b0 ? c[3]  : c[2];
  float t2 = b0 ? c[5]  : c[4],  t3 = b0 ? c[7]  : c[6];
  float t4 = b0 ? c[9]  : c[8],  t5 = b0 ? c[11] : c[10];
  float t6 = b0 ? c[13] : c[12], t7 = b0 ? c[15] : c[14];
  float t8 = b0 ? c[17] : c[16], t9 = b0 ? c[19] : c[18];
  float e0 = b1 ? t1 : t0, e1 = b1 ? t3 : t2, e2 = b1 ? t5 : t4;
  float e3 = b1 ? t7 : t6, e4 = b1 ? t9 : t8;
  const int hi = k >> 2;
  const bool h0 = hi & 1, h1 = hi & 2, h2 = hi & 4;
  float g0 = h0 ? e1 : e0, g1 = h0 ? e3 : e2;
  float m0 = h1 ? g1 : g0;
  return h2 ? e4 : m0;
}

static __device__ __forceinline__ float dppmin(float v, int ctrl){
  int x;
  switch (ctrl){
    case 0xB1:  x = __builtin_amdgcn_update_dpp(0, __float_as_int(v), 0xB1,  0xF, 0xF, true); break;
    case 0x4E:  x = __builtin_amdgcn_update_dpp(0, __float_as_int(v), 0x4E,  0xF, 0xF, true); break;
    case 0x124: x = __builtin_amdgcn_update_dpp(0, __float_as_int(v), 0x124, 0xF, 0xF, true); break;
    default:    x = __builtin_amdgcn_update_dpp(0, __float_as_int(v), 0x128, 0xF, 0xF, true); break;
  }
  return fminf(v, __int_as_float(x));
}

__global__ __launch_bounds__(64) void hungarian(const float* __restrict__ C,
                                                float* __restrict__ rows_out,
                                                float* __restrict__ cols_out){
  const int img  = blockIdx.x;
  const int lane = threadIdx.x;
  const int jA = lane + 1, jB = lane + 65;
  const bool hasB = (jB <= NN);

  float ca[20], cb[20];
  {
    const float* basep = C + (size_t)img * NN * NT + (size_t)lane * NT + img * MT;
    #pragma unroll
    for (int r = 0; r < 5; r++){
      float4 x = *(const float4*)(basep + r*4);
      ca[r*4+0]=x.x; ca[r*4+1]=x.y; ca[r*4+2]=x.z; ca[r*4+3]=x.w;
    }
    if (hasB){
      const float* basep2 = basep + (size_t)64 * NT;
      #pragma unroll
      for (int r = 0; r < 5; r++){
        float4 x = *(const float4*)(basep2 + r*4);
        cb[r*4+0]=x.x; cb[r*4+1]=x.y; cb[r*4+2]=x.z; cb[r*4+3]=x.w;
      }
    } else {
      #pragma unroll
      for (int r = 0; r < 20; r++) cb[r] = 0.f;
    }
  }

  const float INF = 1e30f;
  float vA = 0.f, vB = 0.f;
  float uA = 0.f, uB = 0.f;
  int pA = 0, pB = 0;
  unsigned long long mAmask = 0ull, mBmask = 0ull;

  for (int i = 1; i <= MT; i++){
    float minA = INF, minB = INF;
    int wayA = 0, wayB = 0;
    bool usedA = false, usedB = false;
    float u_i = 0.f;
    int j0 = 0, i0 = i;
    float ui0 = 0.f;

    while (true){
      if (j0 != 0){
        if (j0 <= 64){ if (lane == j0 - 1)  usedA = true; }
        else         { if (lane == j0 - 65) usedB = true; }
      }
      if (!usedA){
        float cur = sel20(ca, i0 - 1) - ui0 - vA;
        if (cur < minA){ minA = cur; wayA = j0; }
      }
      if (hasB && !usedB){
        float cur = sel20(cb, i0 - 1) - ui0 - vB;
        if (cur < minB){ minB = cur; wayB = j0; }
      }
      float candA = usedA ? INF : minA;
      float candB = (hasB && !usedB) ? minB : INF;
      float v = fminf(candA, candB);
      v = dppmin(v, 0xB1);
      v = dppmin(v, 0x4E);
      v = dppmin(v, 0x124);
      v = dppmin(v, 0x128);
      v = fminf(v, __shfl_xor(v, 16));
      v = fminf(v, __shfl_xor(v, 32));
      const float delta = v;
      unsigned long long mAm = __ballot(candA == delta);
      unsigned long long mBm = __ballot(candB == delta);
      const int j1 = mAm ? __ffsll(mAm) : 64 + __ffsll(mBm);
      u_i += delta;
      if (usedA){ vA -= delta; uA += delta; } else minA -= delta;
      if (hasB){ if (usedB){ vB -= delta; uB += delta; } else minB -= delta; }
      j0 = j1;
      bool matched = (j0 <= 64) ? ((mAmask >> (j0 - 1)) & 1ull)
                                : ((mBmask >> (j0 - 65)) & 1ull);
      int   pa = __shfl(pA, (j0 - 1) & 63), pb = __shfl(pB, (j0 - 65) & 63);
      float ua = __shfl(uA, (j0 - 1) & 63), ub = __shfl(uB, (j0 - 65) & 63);
      if (!matched) break;
      i0  = (j0 <= 64) ? pa : pb;
      ui0 = (j0 <= 64) ? ua : ub;
    }
    int j = j0;
    while (true){
      int wjA = __shfl(wayA, (j - 1) & 63);
      int wjB = __shfl(wayB, (j - 65) & 63);
      int wj = (j <= 64) ? wjA : wjB;
      int pv; float uv;
      if (wj == 0){ pv = i; uv = u_i; }
      else {
        int   pa = __shfl(pA, (wj - 1) & 63), pb = __shfl(pB, (wj - 65) & 63);
        float ua = __shfl(uA, (wj - 1) & 63), ub = __shfl(uB, (wj - 65) & 63);
        pv = (wj <= 64) ? pa : pb;
        uv = (wj <= 64) ? ua : ub;
      }
      if (j <= 64){ if (lane == j - 1) { pA = pv; uA = uv; } }
      else        { if (lane == j - 65){ pB = pv; uB = uv; } }
      j = wj;
      if (j == 0) break;
    }
    mAmask = __ballot(pA != 0);
    mBmask = __ballot(hasB && pB != 0);
  }

  unsigned long long lt = (1ull << lane) - 1ull;
  if (pA != 0){
    int rank = __popcll(mAmask & lt);
    rows_out[img * MT + rank] = (float)(jA - 1);
    cols_out[img * MT + rank] = (float)(pA - 1);
  }
  if (hasB && pB != 0){
    int rank = __popcll(mAmask) + __popcll(mBmask & lt);
    rows_out[img * MT + rank] = (float)(jB - 1);
    cols_out[img * MT + rank] = (float)(pB - 1);
  }
}

extern "C" void kernel_launch(void* const* d_in, const int* in_sizes, int n_in,
                              void* d_out, int out_size, void* d_ws, size_t ws_size,
                              hipStream_t stream) {
  const float* pm     = (const float*)d_in[0];
  const float* logits = (const float*)d_in[1];
  const float* tm     = (const float*)d_in[2];
  const int*   tids   = (const int*)d_in[3];

  float* C        = (float*)d_out;
  float* rows_out = C + CNT;
  float* cols_out = rows_out + NB * MT;

  // ws: pnp[KS][800] f32 | tnp2[320] f32 | Bb bf16 | partb bf16[KS][128000]
  static const int ks_opts[] = {80, 40, 20};
  int KS = 20; size_t bb_off = 0, part_off = 0;
  for (int oi = 0; oi < 3; oi++){
    int o = ks_opts[oi];
    size_t small = (size_t)o * NPRED * 4 + 2 * NT * 4;
    size_t bo = (small + 255) & ~(size_t)255;
    size_t po = (bo + (size_t)NT * HW * 2 + 255) & ~(size_t)255;
    size_t need = po + (size_t)o * CNT * 2;
    if (need <= ws_size){ KS = o; bb_off = bo; part_off = po; break; }
  }
  char* ws = (char*)d_ws;
  float* pnp            = (float*)ws;
  float* tnp2           = (float*)(ws + (size_t)KS * NPRED * 4);
  unsigned short* Bb    = (unsigned short*)(ws + bb_off);
  unsigned short* partb = (unsigned short*)(ws + part_off);

  const int Kc = HW / KS;

  conv_b<<<2 * NT, 256, 0, stream>>>(tm, Bb, tnp2);
  if (KS == 80)      gemm_hyb<5><<<MTILES * 80, 256, 0, stream>>>(pm, Bb, partb, pnp, Kc);
  else if (KS == 40) gemm_hyb<10><<<MTILES * 40, 256, 0, stream>>>(pm, Bb, partb, pnp, Kc);
  else               gemm_hyb<20><<<MTILES * 20, 256, 0, stream>>>(pm, Bb, partb, pnp, Kc);
  finalize<<<500, 256, 0, stream>>>(partb, KS, pnp, tnp2, logits, tids, C);
  hungarian<<<NB, 64, 0, stream>>>(C, rows_out, cols_out);
}

// Round 18
// 71.038 us; speedup vs baseline: 1.1963x; 1.1963x over previous
//
#include <hip/hip_runtime.h>
#include <math.h>

#define NB    8
#define NN    100
#define NPRED 800
#define MT    20
#define NT    160
#define HW    25600
#define NCLS  80
#define CNT   (NPRED*NT)  // 128000
#define MTILES 25         // 32-row tiles: 25*32 = 800 exactly
#define REGION 5120       // 32*160 entries per (ks, mtile) region

typedef float  f32x4  __attribute__((ext_vector_type(4)));
typedef short  short8 __attribute__((ext_vector_type(8)));
typedef unsigned short u16x8 __attribute__((ext_vector_type(8)));

static __device__ __forceinline__ unsigned short f2bf_rne(float f){
  unsigned u = __float_as_uint(f);
  return (unsigned short)((u + 0x7fffu + ((u >> 16) & 1u)) >> 16);
}
static __device__ __forceinline__ float bf2f(unsigned short h){
  return __uint_as_float(((unsigned)h) << 16);
}

// async global->LDS, 16B per lane
static __device__ __forceinline__ void gload16(const void* g, void* l){
  __builtin_amdgcn_global_load_lds((const __attribute__((address_space(1))) unsigned int*)g,
                                   (__attribute__((address_space(3))) unsigned int*)l, 16, 0, 0);
}

// ---------------- pre-pass: tm fp32 -> bf16 with BAKED XOR swizzle, half-row partial tnorm ----------------
__global__ __launch_bounds__(256)
void conv_b(const float* __restrict__ tm, unsigned short* __restrict__ Bb,
            float* __restrict__ tnp2){
  const int row = blockIdx.x >> 1, half = blockIdx.x & 1;
  const float4* src = (const float4*)(tm + (size_t)row * HW);
  u16x8* dst = (u16x8*)(Bb + (size_t)row * HW);
  const int sw = row & 7;
  const int g0 = half * 1600, g1 = g0 + 1600;
  float s = 0.f;
  for (int g = g0 + threadIdx.x; g < g1; g += 256){
    float4 x0 = src[g * 2], x1 = src[g * 2 + 1];
    float v[8];
    v[0]=x0.x; v[1]=x0.y; v[2]=x0.z; v[3]=x0.w;
    v[4]=x1.x; v[5]=x1.y; v[6]=x1.z; v[7]=x1.w;
    u16x8 h;
    #pragma unroll
    for (int i = 0; i < 8; i++){ s += v[i]*v[i]; h[i] = f2bf_rne(v[i]); }
    dst[(g & ~7) | ((g & 7) ^ sw)] = h;
  }
  __shared__ float red[256];
  red[threadIdx.x] = s; __syncthreads();
  for (int off = 128; off > 0; off >>= 1){
    if (threadIdx.x < off) red[threadIdx.x] += red[threadIdx.x + off];
    __syncthreads();
  }
  if (threadIdx.x == 0) tnp2[half * NT + row] = red[0];
}

// ---------------- hybrid GEMM, 32-row tiles, fragment-order bf16 part store ----------------
// Tile 32x160x64; 4 waves 2x2, wave tile 16x80. LDS 24 KiB. Grid 1000 (~4/CU).
// partb layout: [ks][mtile][w][c][i][lane] -> every store is a full 128B line (no write-amp).
template<int KSTEPS>
__global__ __launch_bounds__(256, 6)
void gemm_hyb(const float* __restrict__ A, const unsigned short* __restrict__ Bb,
              unsigned short* __restrict__ partb, float* __restrict__ pnp, int Kc){
  __shared__ unsigned short sA[32*64];    // 4 KB
  __shared__ unsigned short sB[160*64];   // 20 KB

  const int bid = blockIdx.x;
  const int nb  = gridDim.x;
  const int wg  = ((nb & 7) == 0) ? (bid & 7) * (nb >> 3) + (bid >> 3) : bid;  // XCD-bijective
  const int mtile = wg % MTILES, ks = wg / MTILES;
  const int t = threadIdx.x, lane = t & 63, w = t >> 6;
  const int wr = w >> 1, wc = w & 1;
  const int fr = lane & 15, fq = lane >> 4;
  const int arow = t >> 3, ksl = t & 7;    // A staging: 32 rows x 8 slots
  const int kbase = ks * Kc;

  f32x4 acc[5];
  #pragma unroll
  for (int c = 0; c < 5; c++) acc[c] = (f32x4){0.f,0.f,0.f,0.f};
  float asum = 0.f;

  int brow[5], bg[5];
  #pragma unroll
  for (int i = 0; i < 5; i++){ int s2 = t + i * 256; brow[i] = s2 >> 3; bg[i] = s2 & 7; }

  const float4* ap = (const float4*)(A + (size_t)(mtile*32 + arow) * HW + kbase + ksl * 8);

  for (int step = 0; step < KSTEPS; ++step){
    const int k0 = kbase + step * 64;
    #pragma unroll
    for (int i = 0; i < 5; i++)
      gload16(Bb + (size_t)brow[i] * HW + k0 + bg[i] * 8, sB + (t + i * 256) * 8);
    {
      float4 x0 = ap[step * 16];
      float4 x1 = ap[step * 16 + 1];
      float v[8];
      v[0]=x0.x; v[1]=x0.y; v[2]=x0.z; v[3]=x0.w;
      v[4]=x1.x; v[5]=x1.y; v[6]=x1.z; v[7]=x1.w;
      u16x8 h;
      #pragma unroll
      for (int i = 0; i < 8; i++){ asum += v[i]*v[i]; h[i] = f2bf_rne(v[i]); }
      *(u16x8*)&sA[arow * 64 + ((ksl ^ (arow & 7)) << 3)] = h;
    }
    __syncthreads();
    #pragma unroll
    for (int kk = 0; kk < 2; ++kk){
      const int swz = (((kk * 4 + fq) ^ (fr & 7)) << 3);
      short8 a = *(const short8*)&sA[(wr*16 + fr) * 64 + swz];
      short8 b[5];
      #pragma unroll
      for (int c = 0; c < 5; c++)
        b[c] = *(const short8*)&sB[(wc*80 + c*16 + fr) * 64 + swz];
      #pragma unroll
      for (int c = 0; c < 5; c++)
        acc[c] = __builtin_amdgcn_mfma_f32_16x16x32_bf16(a, b[c], acc[c], 0, 0, 0);
    }
    __syncthreads();
  }

  // pnorm partials
  {
    float s = asum;
    s += __shfl_xor(s, 1); s += __shfl_xor(s, 2); s += __shfl_xor(s, 4);
    if ((t & 7) == 0) pnp[(size_t)ks * NPRED + mtile*32 + arow] = s;
  }

  // fragment-order store: each (c,i) store = 64 lanes x 2B = one full 128B line
  unsigned short* dst = partb + (size_t)ks * CNT + (size_t)mtile * REGION;
  #pragma unroll
  for (int c = 0; c < 5; c++)
    #pragma unroll
    for (int i = 0; i < 4; i++)
      dst[((w * 5 + c) * 4 + i) * 64 + lane] = f2bf_rne(acc[c][i]);
}

// ---------------- finalize (separate kernel; fragment-order partb) ----------------
__global__ __launch_bounds__(256)
void finalize(const unsigned short* __restrict__ partb, int KS,
              const float* __restrict__ pnp, const float* __restrict__ tnp2,
              const float* __restrict__ logits, const int* __restrict__ tgt_ids,
              float* __restrict__ C){
  __shared__ float stn[NT];
  __shared__ float spn[32];
  const int blk = blockIdx.x, t = threadIdx.x;
  const int mtile = blk / 20;
  if (t < NT){
    stn[t] = tnp2[t] + tnp2[NT + t];
  } else if (t < NT + 32){
    const int p = mtile * 32 + (t - NT);
    float s = 0.f;
    for (int ks = 0; ks < KS; ks++) s += pnp[(size_t)ks * NPRED + p];
    spn[t - NT] = s;
  }
  __syncthreads();

  const int idx = blk * 256 + t;
  const int rem  = idx - mtile * REGION;
  const int w2   = rem / 1280;
  const int rem2 = rem - w2 * 1280;
  const int c    = rem2 >> 8;
  const int rem3 = rem2 & 255;
  const int i    = rem3 >> 6;
  const int lane = rem3 & 63;
  const int wr = w2 >> 1, wc = w2 & 1;
  const int fq = lane >> 4, fr = lane & 15;
  const int pl_ = wr*16 + fq*4 + i;
  const int pred = mtile*32 + pl_;
  const int tt   = wc*80 + c*16 + fr;

  const unsigned short* p = partb + idx;
  double d0=0.0, d1=0.0, d2=0.0, d3=0.0;
  int ks = 0;
  for (; ks + 4 <= KS; ks += 4){
    d0 += (double)bf2f(p[(size_t)(ks+0) * CNT]);
    d1 += (double)bf2f(p[(size_t)(ks+1) * CNT]);
    d2 += (double)bf2f(p[(size_t)(ks+2) * CNT]);
    d3 += (double)bf2f(p[(size_t)(ks+3) * CNT]);
  }
  for (; ks < KS; ks++) d0 += (double)bf2f(p[(size_t)ks * CNT]);
  double dot = (d0 + d1) + (d2 + d3);
  double num = 2.0 * dot;
  double den = (double)spn[pl_] + (double)stn[tt];
  double mask_score = -((num + 1e-4) / (den + 1e-4));
  double x = (double)logits[pred * NCLS + tgt_ids[tt]];
  double pl = 1.0 / (1.0 + exp(-x));
  double pos = 0.25 * (1.0 - pl) * (1.0 - pl) * (-log(pl + 1e-8));
  double neg = 0.75 * pl * pl * (-log(1.0 - pl + 1e-8));
  double cv = mask_score * 2.0 + (pos - neg);
  float o = (float)cv;
  if (!isfinite(o)) o = 0.0f;
  C[(size_t)pred * NT + tt] = o;
}

// ---------------- Hungarian (JV): fp32 regs, DPP min + ballot argmin, packed (p,u) ----------------
static __device__ __forceinline__ float sel20(const float c[20], int k){
  const bool b0 = k & 1, b1 = k & 2;
  float t0 = b0 ? c[1]  : c[0],  t1 = b0 ? c[3]  : c[2];
  float t2 = b0 ? c[5]  : c[4],  t3 = b0 ? c[7]  : c[6];
  float t4 = b0 ? c[9]  : c[8],  t5 = b0 ? c[11] : c[10];
  float t6 = b0 ? c[13] : c[12], t7 = b0 ? c[15] : c[14];
  float t8 = b0 ? c[17] : c[16], t9 = b0 ? c[19] : c[18];
  float e0 = b1 ? t1 : t0, e1 = b1 ? t3 : t2, e2 = b1 ? t5 : t4;
  float e3 = b1 ? t7 : t6, e4 = b1 ? t9 : t8;
  const int hi = k >> 2;
  const bool h0 = hi & 1, h1 = hi & 2, h2 = hi & 4;
  float g0 = h0 ? e1 : e0, g1 = h0 ? e3 : e2;
  float m0 = h1 ? g1 : g0;
  return h2 ? e4 : m0;
}

static __device__ __forceinline__ float dppmin(float v, int ctrl){
  int x;
  switch (ctrl){
    case 0xB1:  x = __builtin_amdgcn_update_dpp(0, __float_as_int(v), 0xB1,  0xF, 0xF, true); break;
    case 0x4E:  x = __builtin_amdgcn_update_dpp(0, __float_as_int(v), 0x4E,  0xF, 0xF, true); break;
    case 0x124: x = __builtin_amdgcn_update_dpp(0, __float_as_int(v), 0x124, 0xF, 0xF, true); break;
    default:    x = __builtin_amdgcn_update_dpp(0, __float_as_int(v), 0x128, 0xF, 0xF, true); break;
  }
  return fminf(v, __int_as_float(x));
}

__global__ __launch_bounds__(64) void hungarian(const float* __restrict__ C,
                                                float* __restrict__ rows_out,
                                                float* __restrict__ cols_out){
  const int img  = blockIdx.x;
  const int lane = threadIdx.x;
  const int jA = lane + 1, jB = lane + 65;
  const bool hasB = (jB <= NN);

  float ca[20], cb[20];
  {
    const float* basep = C + (size_t)img * NN * NT + (size_t)lane * NT + img * MT;
    #pragma unroll
    for (int r = 0; r < 5; r++){
      float4 x = *(const float4*)(basep + r*4);
      ca[r*4+0]=x.x; ca[r*4+1]=x.y; ca[r*4+2]=x.z; ca[r*4+3]=x.w;
    }
    if (hasB){
      const float* basep2 = basep + (size_t)64 * NT;
      #pragma unroll
      for (int r = 0; r < 5; r++){
        float4 x = *(const float4*)(basep2 + r*4);
        cb[r*4+0]=x.x; cb[r*4+1]=x.y; cb[r*4+2]=x.z; cb[r*4+3]=x.w;
      }
    } else {
      #pragma unroll
      for (int r = 0; r < 20; r++) cb[r] = 0.f;
    }
  }

  const float INF = 1e30f;
  float vA = 0.f, vB = 0.f;
  float uA = 0.f, uB = 0.f;
  int pA = 0, pB = 0;
  unsigned long long mAmask = 0ull, mBmask = 0ull;

  for (int i = 1; i <= MT; i++){
    float minA = INF, minB = INF;
    int wayA = 0, wayB = 0;
    bool usedA = false, usedB = false;
    float u_i = 0.f;
    int j0 = 0, i0 = i;
    float ui0 = 0.f;

    while (true){
      if (j0 != 0){
        if (j0 <= 64){ if (lane == j0 - 1)  usedA = true; }
        else         { if (lane == j0 - 65) usedB = true; }
      }
      if (!usedA){
        float cur = sel20(ca, i0 - 1) - ui0 - vA;
        if (cur < minA){ minA = cur; wayA = j0; }
      }
      if (hasB && !usedB){
        float cur = sel20(cb, i0 - 1) - ui0 - vB;
        if (cur < minB){ minB = cur; wayB = j0; }
      }
      float candA = usedA ? INF : minA;
      float candB = (hasB && !usedB) ? minB : INF;
      float v = fminf(candA, candB);
      v = dppmin(v, 0xB1);
      v = dppmin(v, 0x4E);
      v = dppmin(v, 0x124);
      v = dppmin(v, 0x128);
      v = fminf(v, __shfl_xor(v, 16));
      v = fminf(v, __shfl_xor(v, 32));
      const float delta = v;
      unsigned long long mAm = __ballot(candA == delta);
      unsigned long long mBm = __ballot(candB == delta);
      const int j1 = mAm ? __ffsll(mAm) : 64 + __ffsll(mBm);
      u_i += delta;
      if (usedA){ vA -= delta; uA += delta; } else minA -= delta;
      if (hasB){ if (usedB){ vB -= delta; uB += delta; } else minB -= delta; }
      j0 = j1;
      bool matched = (j0 <= 64) ? ((mAmask >> (j0 - 1)) & 1ull)
                                : ((mBmask >> (j0 - 65)) & 1ull);
      int   pa = __shfl(pA, (j0 - 1) & 63), pb = __shfl(pB, (j0 - 65) & 63);
      float ua = __shfl(uA, (j0 - 1) & 63), ub = __shfl(uB, (j0 - 65) & 63);
      if (!matched) break;
      i0  = (j0 <= 64) ? pa : pb;
      ui0 = (j0 <= 64) ? ua : ub;
    }
    int j = j0;
    while (true){
      int wjA = __shfl(wayA, (j - 1) & 63);
      int wjB = __shfl(wayB, (j - 65) & 63);
      int wj = (j <= 64) ? wjA : wjB;
      int pv; float uv;
      if (wj == 0){ pv = i; uv = u_i; }
      else {
        int   pa = __shfl(pA, (wj - 1) & 63), pb = __shfl(pB, (wj - 65) & 63);
        float ua = __shfl(uA, (wj - 1) & 63), ub = __shfl(uB, (wj - 65) & 63);
        pv = (wj <= 64) ? pa : pb;
        uv = (wj <= 64) ? ua : ub;
      }
      if (j <= 64){ if (lane == j - 1) { pA = pv; uA = uv; } }
      else        { if (lane == j - 65){ pB = pv; uB = uv; } }
      j = wj;
      if (j == 0) break;
    }
    mAmask = __ballot(pA != 0);
    mBmask = __ballot(hasB && pB != 0);
  }

  unsigned long long lt = (1ull << lane) - 1ull;
  if (pA != 0){
    int rank = __popcll(mAmask & lt);
    rows_out[img * MT + rank] = (float)(jA - 1);
    cols_out[img * MT + rank] = (float)(pA - 1);
  }
  if (hasB && pB != 0){
    int rank = __popcll(mAmask) + __popcll(mBmask & lt);
    rows_out[img * MT + rank] = (float)(jB - 1);
    cols_out[img * MT + rank] = (float)(pB - 1);
  }
}

extern "C" void kernel_launch(void* const* d_in, const int* in_sizes, int n_in,
                              void* d_out, int out_size, void* d_ws, size_t ws_size,
                              hipStream_t stream) {
  const float* pm     = (const float*)d_in[0];
  const float* logits = (const float*)d_in[1];
  const float* tm     = (const float*)d_in[2];
  const int*   tids   = (const int*)d_in[3];

  float* C        = (float*)d_out;
  float* rows_out = C + CNT;
  float* cols_out = rows_out + NB * MT;

  // ws: pnp[KS][800] f32 | tnp2[320] f32 | Bb bf16 | partb bf16[KS][128000]
  static const int ks_opts[] = {40, 20, 10};
  int KS = 10; size_t bb_off = 0, part_off = 0;
  for (int oi = 0; oi < 3; oi++){
    int o = ks_opts[oi];
    size_t small = (size_t)o * NPRED * 4 + 2 * NT * 4;
    size_t bo = (small + 255) & ~(size_t)255;
    size_t po = (bo + (size_t)NT * HW * 2 + 255) & ~(size_t)255;
    size_t need = po + (size_t)o * CNT * 2;
    if (need <= ws_size){ KS = o; bb_off = bo; part_off = po; break; }
  }
  char* ws = (char*)d_ws;
  float* pnp            = (float*)ws;
  float* tnp2           = (float*)(ws + (size_t)KS * NPRED * 4);
  unsigned short* Bb    = (unsigned short*)(ws + bb_off);
  unsigned short* partb = (unsigned short*)(ws + part_off);

  const int Kc = HW / KS;

  conv_b<<<2 * NT, 256, 0, stream>>>(tm, Bb, tnp2);
  if (KS == 40)      gemm_hyb<10><<<MTILES * 40, 256, 0, stream>>>(pm, Bb, partb, pnp, Kc);
  else if (KS == 20) gemm_hyb<20><<<MTILES * 20, 256, 0, stream>>>(pm, Bb, partb, pnp, Kc);
  else               gemm_hyb<40><<<MTILES * 10, 256, 0, stream>>>(pm, Bb, partb, pnp, Kc);
  finalize<<<500, 256, 0, stream>>>(partb, KS, pnp, tnp2, logits, tids, C);
  hungarian<<<NB, 64, 0, stream>>>(C, rows_out, cols_out);
}